// Round 1
// baseline (706.890 us; speedup 1.0000x reference)
//
#include <hip/hip_runtime.h>
#include <float.h>

#define NSEG 8
#define SEGLEN 1024  // B*Ls*H*D = 1*4*8*32
#define EPL 16       // elements (columns) per lane; 64 lanes * 16 = 1024 cols

__device__ __forceinline__ float wave_incl_add(float v, int lane) {
#pragma unroll
    for (int off = 1; off < 64; off <<= 1) {
        float n = __shfl_up(v, off);
        if (lane >= off) v += n;
    }
    return v;
}

__device__ __forceinline__ float wave_incl_min(float v, int lane) {
#pragma unroll
    for (int off = 1; off < 64; off <<= 1) {
        float n = __shfl_up(v, off);
        if (lane >= off) v = fminf(v, n);
    }
    return v;
}

// One wave per (qi, kj) pair. Exact DTW via per-row min-plus prefix scan:
//   d[i,:] = S + cummin(a + c - S),  a[j]=min(prev[j],prev[j-1]), S=cumsum(c)
// Refactored per lane (16 cols each) with c[k]-ls[k] == -ls[k-1]:
//   f[k]  = min(prev[k], prev[k-1]) - ls[k-1]
//   d[k]  = ls[k] + min(carry + lpe, local_cummin(f)[k])
__global__ __launch_bounds__(64) void dtw_kernel(const float* __restrict__ q,
                                                 const float* __restrict__ kk,
                                                 float* __restrict__ dists) {
    const int lane = threadIdx.x;
    const int pair = blockIdx.x;          // 0..63
    const int qi = pair >> 3;
    const int kj = pair & 7;
    const float* __restrict__ x = q + qi * SEGLEN;
    const float* __restrict__ y = kk + kj * SEGLEN;

    // lane owns columns [lane*16, lane*16+16)
    float yv[EPL];
#pragma unroll
    for (int e = 0; e < EPL; ++e) yv[e] = y[lane * EPL + e];

    float prev[EPL];

    // ---- row 0: prev = cumsum(c) ----
    {
        const float xi = x[0];
        float ls[EPL];
        float run = 0.f;
#pragma unroll
        for (int e = 0; e < EPL; ++e) { run += fabsf(xi - yv[e]); ls[e] = run; }
        float incl = wave_incl_add(run, lane);
        float lpe = __shfl_up(incl, 1);
        if (lane == 0) lpe = 0.f;
#pragma unroll
        for (int e = 0; e < EPL; ++e) prev[e] = lpe + ls[e];
    }

    // ---- rows 1..1023 ----
    for (int row = 1; row < SEGLEN; ++row) {
        const float xi = x[row];          // wave-uniform -> scalar load
        float ls[EPL], lm[EPL];

        // local cumsum of costs
        float run = 0.f;
#pragma unroll
        for (int e = 0; e < EPL; ++e) { run += fabsf(xi - yv[e]); ls[e] = run; }

        // wave exclusive-cumsum of lane totals
        float incl = wave_incl_add(run, lane);
        float lpe = __shfl_up(incl, 1);
        if (lane == 0) lpe = 0.f;

        // shifted prev across lane boundary
        float pm1 = __shfl_up(prev[EPL - 1], 1);
        if (lane == 0) pm1 = FLT_MAX;     // reference's `big` sentinel at j=-1

        // f[k] = min(prev[k], prev[k-1]) - ls[k-1]; local cummin
        float runm = FLT_MAX;
        float lsm1 = 0.f;
#pragma unroll
        for (int e = 0; e < EPL; ++e) {
            float a = fminf(prev[e], (e == 0) ? pm1 : prev[e - 1]);
            float f = a - lsm1;
            runm = fminf(runm, f);
            lm[e] = runm;
            lsm1 = ls[e];
        }

        // wave exclusive-cummin of per-lane (min_f - lpe)
        float minc = wave_incl_min(runm - lpe, lane);
        float carry = __shfl_up(minc, 1);
        if (lane == 0) carry = FLT_MAX;

        const float t = carry + lpe;
#pragma unroll
        for (int e = 0; e < EPL; ++e) prev[e] = ls[e] + fminf(t, lm[e]);
    }

    if (lane == 63) dists[pair] = prev[EPL - 1];
}

// out[i*1024+p] = sum_j softmax_j(0.5*dists[i,:])[j] * values[j*1024+p]
__global__ __launch_bounds__(256) void softmax_out_kernel(const float* __restrict__ v,
                                                          const float* __restrict__ dists,
                                                          float* __restrict__ out) {
    const int o = blockIdx.x * blockDim.x + threadIdx.x;
    if (o >= NSEG * SEGLEN) return;
    const int i = o >> 10;       // output segment
    const int p = o & 1023;      // position within segment

    float l[NSEG];
    float mx = -FLT_MAX;
#pragma unroll
    for (int j = 0; j < NSEG; ++j) {
        l[j] = 0.5f * dists[i * NSEG + j];
        mx = fmaxf(mx, l[j]);
    }
    float s = 0.f;
#pragma unroll
    for (int j = 0; j < NSEG; ++j) {
        l[j] = expf(l[j] - mx);
        s += l[j];
    }
    const float inv = 1.f / s;
    float acc = 0.f;
#pragma unroll
    for (int j = 0; j < NSEG; ++j) acc += (l[j] * inv) * v[j * SEGLEN + p];
    out[o] = acc;
}

extern "C" void kernel_launch(void* const* d_in, const int* in_sizes, int n_in,
                              void* d_out, int out_size, void* d_ws, size_t ws_size,
                              hipStream_t stream) {
    const float* q = (const float*)d_in[0];   // queries [1,32,8,32]
    const float* k = (const float*)d_in[1];   // keys    [1,32,8,32]
    const float* v = (const float*)d_in[2];   // values  [1,32,8,32]
    // d_in[3] = attn_mask (unused, as in reference)
    float* out = (float*)d_out;               // [8192] f32
    float* dists = (float*)d_ws;              // 64 floats scratch

    dtw_kernel<<<dim3(NSEG * NSEG), dim3(64), 0, stream>>>(q, k, dists);
    softmax_out_kernel<<<dim3((NSEG * SEGLEN + 255) / 256), dim3(256), 0, stream>>>(v, dists, out);
}

// Round 2
// 268.826 us; speedup vs baseline: 2.6295x; 2.6295x over previous
//
#include <hip/hip_runtime.h>
#include <float.h>

#define NSEG 8
#define SEGLEN 1024  // B*Ls*H*D = 1*4*8*32
#define EPL 16       // columns per lane; 64 lanes * 16 = 1024 cols

// DPP helper: result = for each lane, src moved per CTRL; lanes masked off by
// RM/BM (or with invalid source when BC==false) receive OLD. BC==true -> 0.
#define DPPF(OLD, SRC, CTRL, RM, BM, BC)                                      \
    __int_as_float(__builtin_amdgcn_update_dpp(                               \
        __float_as_int(OLD), __float_as_int(SRC), CTRL, RM, BM, BC))

// wave64 inclusive add-scan: 4x row_shr + row_bcast:15 + row_bcast:31
__device__ __forceinline__ float scan_add64(float v) {
    v += DPPF(0.f, v, 0x111, 0xF, 0xF, true);   // row_shr:1
    v += DPPF(0.f, v, 0x112, 0xF, 0xF, true);   // row_shr:2
    v += DPPF(0.f, v, 0x114, 0xF, 0xF, true);   // row_shr:4
    v += DPPF(0.f, v, 0x118, 0xF, 0xF, true);   // row_shr:8
    v += DPPF(0.f, v, 0x142, 0xA, 0xF, true);   // row_bcast:15 -> rows 1,3
    v += DPPF(0.f, v, 0x143, 0xC, 0xF, true);   // row_bcast:31 -> rows 2,3
    return v;
}

// wave64 inclusive min-scan: identity (+FLT_MAX) via OLD, bound_ctrl off
__device__ __forceinline__ float scan_min64(float v) {
    v = fminf(v, DPPF(FLT_MAX, v, 0x111, 0xF, 0xF, false));
    v = fminf(v, DPPF(FLT_MAX, v, 0x112, 0xF, 0xF, false));
    v = fminf(v, DPPF(FLT_MAX, v, 0x114, 0xF, 0xF, false));
    v = fminf(v, DPPF(FLT_MAX, v, 0x118, 0xF, 0xF, false));
    v = fminf(v, DPPF(FLT_MAX, v, 0x142, 0xA, 0xF, false));
    v = fminf(v, DPPF(FLT_MAX, v, 0x143, 0xC, 0xF, false));
    return v;
}

// whole-wave shift right by 1 (wf_sr1); lane 0 receives OLD
#define WSHIFT1(OLD, SRC) DPPF(OLD, SRC, 0x138, 0xF, 0xF, false)

// One wave per (qi, kj) pair. Exact DTW via per-row min-plus prefix scan:
//   d[i,:] = S + cummin(a + c - S),  a[j]=min(prev[j],prev[j-1]), S=cumsum(c)
// Per lane (16 cols each), using c[k]-ls[k] == -ls[k-1]:
//   f[k]  = min(prev[k], prev[k-1]) - ls[k-1]
//   d[k]  = ls[k] + min(carry + lpe, local_cummin(f)[k])
__global__ __launch_bounds__(64) void dtw_kernel(const float* __restrict__ q,
                                                 const float* __restrict__ kk,
                                                 float* __restrict__ dists) {
    const int lane = threadIdx.x;
    const int pair = blockIdx.x;          // 0..63
    const int qi = pair >> 3;
    const int kj = pair & 7;
    const float* __restrict__ x = q + qi * SEGLEN;
    const float* __restrict__ y = kk + kj * SEGLEN;

    float yv[EPL];
#pragma unroll
    for (int e = 0; e < EPL; ++e) yv[e] = y[lane * EPL + e];

    float prev[EPL];

    // ---- row 0: prev = cumsum(c) ----
    {
        const float xi = x[0];
        float ls[EPL];
        float run = 0.f;
#pragma unroll
        for (int e = 0; e < EPL; ++e) { run += fabsf(xi - yv[e]); ls[e] = run; }
        float incl = scan_add64(run);
        float lpe = WSHIFT1(0.f, incl);
#pragma unroll
        for (int e = 0; e < EPL; ++e) prev[e] = lpe + ls[e];
    }

    // ---- rows 1..1023 ----
#pragma unroll 2
    for (int row = 1; row < SEGLEN; ++row) {
        const float xi = x[row];          // wave-uniform
        float ls[EPL], lm[EPL];

        // local cumsum of costs
        float run = 0.f;
#pragma unroll
        for (int e = 0; e < EPL; ++e) { run += fabsf(xi - yv[e]); ls[e] = run; }

        // wave exclusive-cumsum of lane totals
        float lpe = WSHIFT1(0.f, scan_add64(run));

        // shifted prev across lane boundary (lane0 gets +inf sentinel)
        float pm1 = WSHIFT1(FLT_MAX, prev[EPL - 1]);

        // f[k] = min(prev[k], prev[k-1]) - ls[k-1]; local cummin
        float runm = FLT_MAX;
        float lsm1 = 0.f;
#pragma unroll
        for (int e = 0; e < EPL; ++e) {
            float a = fminf(prev[e], (e == 0) ? pm1 : prev[e - 1]);
            float f = a - lsm1;
            runm = fminf(runm, f);
            lm[e] = runm;
            lsm1 = ls[e];
        }

        // wave exclusive-cummin of per-lane (min_f - lpe)
        float carry = WSHIFT1(FLT_MAX, scan_min64(runm - lpe));

        const float t = carry + lpe;
#pragma unroll
        for (int e = 0; e < EPL; ++e) prev[e] = ls[e] + fminf(t, lm[e]);
    }

    if (lane == 63) dists[pair] = prev[EPL - 1];
}

// out[i*1024+p] = sum_j softmax_j(0.5*dists[i,:])[j] * values[j*1024+p]
__global__ __launch_bounds__(256) void softmax_out_kernel(const float* __restrict__ v,
                                                          const float* __restrict__ dists,
                                                          float* __restrict__ out) {
    const int o = blockIdx.x * blockDim.x + threadIdx.x;
    if (o >= NSEG * SEGLEN) return;
    const int i = o >> 10;
    const int p = o & 1023;

    float l[NSEG];
    float mx = -FLT_MAX;
#pragma unroll
    for (int j = 0; j < NSEG; ++j) {
        l[j] = 0.5f * dists[i * NSEG + j];
        mx = fmaxf(mx, l[j]);
    }
    float s = 0.f;
#pragma unroll
    for (int j = 0; j < NSEG; ++j) {
        l[j] = expf(l[j] - mx);
        s += l[j];
    }
    const float inv = 1.f / s;
    float acc = 0.f;
#pragma unroll
    for (int j = 0; j < NSEG; ++j) acc += (l[j] * inv) * v[j * SEGLEN + p];
    out[o] = acc;
}

extern "C" void kernel_launch(void* const* d_in, const int* in_sizes, int n_in,
                              void* d_out, int out_size, void* d_ws, size_t ws_size,
                              hipStream_t stream) {
    const float* q = (const float*)d_in[0];   // queries [1,32,8,32] f32
    const float* k = (const float*)d_in[1];   // keys
    const float* v = (const float*)d_in[2];   // values
    float* out = (float*)d_out;               // [8192] f32
    float* dists = (float*)d_ws;              // 64 floats scratch

    dtw_kernel<<<dim3(NSEG * NSEG), dim3(64), 0, stream>>>(q, k, dists);
    softmax_out_kernel<<<dim3((NSEG * SEGLEN + 255) / 256), dim3(256), 0, stream>>>(v, dists, out);
}

// Round 3
// 211.019 us; speedup vs baseline: 3.3499x; 1.2739x over previous
//
#include <hip/hip_runtime.h>
#include <float.h>

#define NSEG 8
#define SEGLEN 1024  // B*Ls*H*D = 1*4*8*32
#define EPL 16       // columns per lane; 64 lanes * 16 = 1024 cols
#define BIGV 1e30f   // "infinity" for invalid DP cells
#define PADV 1e18f   // x-pad sentinel: cost |PADV-y| is huge, sums stay < FLT_MAX

#define DPPF(OLD, SRC, CTRL, RM, BM, BC)                                      \
    __int_as_float(__builtin_amdgcn_update_dpp(                               \
        __float_as_int(OLD), __float_as_int(SRC), CTRL, RM, BM, BC))
// whole-wave shift right by 1 (wf_sr1); lane 0 receives OLD
#define WSHIFT1(OLD, SRC) DPPF(OLD, SRC, 0x138, 0xF, 0xF, false)

// One wave per (qi,kj) pair. Anti-diagonal DP:
//   D[i,j] = |x[i]-y[j]| + min3(D[i-1,j], D[i,j-1], D[i-1,j-1])
// Diagonal d holds cells (d-j, j); lane L owns j in [16L,16L+16).
// prev1 = diagonal d-1, prev2 = d-2. Per step per cell: sub, min3, add(|.|).
// Invalid cells (i<0 or i>1023) read PADV from the padded LDS x copy -> huge.
__global__ __launch_bounds__(64) void dtw_diag_kernel(const float* __restrict__ q,
                                                      const float* __restrict__ kk,
                                                      float* __restrict__ dists) {
    __shared__ float xe[3072];  // xe[t] = x[t-1024] for t in [1024,2048), else PADV
    const int lane = threadIdx.x;
    const int pair = blockIdx.x;          // 0..63
    const int qi = pair >> 3;
    const int kj = pair & 7;
    const float* __restrict__ x = q + qi * SEGLEN;
    const float* __restrict__ y = kk + kj * SEGLEN;

    for (int t = lane; t < 3072; t += 64) {
        int i = t - 1024;
        xe[t] = (i >= 0 && i < SEGLEN) ? x[i] : PADV;
    }
    __syncthreads();

    float yv[EPL];
#pragma unroll
    for (int e = 0; e < EPL; ++e) yv[e] = y[lane * EPL + e];

    float A[EPL], B[EPL];   // ping-pong diagonals
#pragma unroll
    for (int e = 0; e < EPL; ++e) { A[e] = BIGV; B[e] = BIGV; }

    // window: xw[t] = xe[wbase + db + t]; cost(s,e) uses xw[s - e + 16]
    const int wbase = 1024 - 16 * lane - 16;

    for (int db = 0; db < 2048; db += 16) {   // 128 blocks x 16 diagonals
        float xw[32];
        const float4* wp = (const float4*)&xe[wbase + db];
#pragma unroll
        for (int c = 0; c < 8; ++c) ((float4*)xw)[c] = wp[c];

#pragma unroll
        for (int s = 0; s < 16; ++s) {
            if ((s & 1) == 0) {
                // prev1 = A (d-1), prev2 = B (d-2), out = B; descending e so
                // B[e-1] (diag) is read before B[e-1] is overwritten.
                float p1m = WSHIFT1(BIGV, A[EPL - 1]);
                // cell (0,0): its diag neighbor is the virtual D[-1,-1] = 0
                float sh2 = (s == 0) ? ((db == 0) ? 0.f : BIGV) : BIGV;
                float p2m = WSHIFT1(sh2, B[EPL - 1]);
#pragma unroll
                for (int e = EPL - 1; e >= 0; --e) {
                    float up = A[e];
                    float lf = (e == 0) ? p1m : A[e - 1];
                    float dg = (e == 0) ? p2m : B[e - 1];
                    float m = fminf(fminf(up, lf), dg);   // v_min3_f32
                    B[e] = fabsf(xw[s - e + 16] - yv[e]) + m;
                }
            } else {
                float p1m = WSHIFT1(BIGV, B[EPL - 1]);
                float p2m = WSHIFT1(BIGV, A[EPL - 1]);
#pragma unroll
                for (int e = EPL - 1; e >= 0; --e) {
                    float up = B[e];
                    float lf = (e == 0) ? p1m : B[e - 1];
                    float dg = (e == 0) ? p2m : A[e - 1];
                    float m = fminf(fminf(up, lf), dg);
                    A[e] = fabsf(xw[s - e + 16] - yv[e]) + m;
                }
            }
        }
    }
    // Cell (1023,1023) is diagonal d=2046 (even) -> landed in B.
    if (lane == 63) dists[pair] = B[EPL - 1];
}

// out[i*1024+p] = sum_j softmax_j(0.5*dists[i,:])[j] * values[j*1024+p]
__global__ __launch_bounds__(256) void softmax_out_kernel(const float* __restrict__ v,
                                                          const float* __restrict__ dists,
                                                          float* __restrict__ out) {
    const int o = blockIdx.x * blockDim.x + threadIdx.x;
    if (o >= NSEG * SEGLEN) return;
    const int i = o >> 10;
    const int p = o & 1023;

    float l[NSEG];
    float mx = -FLT_MAX;
#pragma unroll
    for (int j = 0; j < NSEG; ++j) {
        l[j] = 0.5f * dists[i * NSEG + j];
        mx = fmaxf(mx, l[j]);
    }
    float s = 0.f;
#pragma unroll
    for (int j = 0; j < NSEG; ++j) {
        l[j] = expf(l[j] - mx);
        s += l[j];
    }
    const float inv = 1.f / s;
    float acc = 0.f;
#pragma unroll
    for (int j = 0; j < NSEG; ++j) acc += (l[j] * inv) * v[j * SEGLEN + p];
    out[o] = acc;
}

extern "C" void kernel_launch(void* const* d_in, const int* in_sizes, int n_in,
                              void* d_out, int out_size, void* d_ws, size_t ws_size,
                              hipStream_t stream) {
    const float* q = (const float*)d_in[0];   // queries [1,32,8,32] f32
    const float* k = (const float*)d_in[1];   // keys
    const float* v = (const float*)d_in[2];   // values
    float* out = (float*)d_out;               // [8192] f32
    float* dists = (float*)d_ws;              // 64 floats scratch

    dtw_diag_kernel<<<dim3(NSEG * NSEG), dim3(64), 0, stream>>>(q, k, dists);
    softmax_out_kernel<<<dim3((NSEG * SEGLEN + 255) / 256), dim3(256), 0, stream>>>(v, dists, out);
}

// Round 4
// 132.120 us; speedup vs baseline: 5.3503x; 1.5972x over previous
//
#include <hip/hip_runtime.h>
#include <float.h>

#define NSEG 8
#define SEGLEN 1024   // B*Ls*H*D = 1*4*8*32
#define BIGV 1e30f    // "infinity" for invalid DP cells
#define PADV 1e18f    // x-pad sentinel (huge cost, no overflow)

#define CH 32         // diagonals per chunk
#define NCH 40        // chunks per wave: (1024+256-1+pad)/32 = 1280/32
#define LAG 9         // chunk skew between adjacent waves
#define NSUP (NCH + 3 * LAG)  // 67 supersteps
#define BSTRIDE 1540  // boundary array stride (rows -256..1283 padded)
#define BOFF 256      // boundary row-index offset

#define DPPF(OLD, SRC, CTRL, RM, BM, BC)                                      \
    __int_as_float(__builtin_amdgcn_update_dpp(                               \
        __float_as_int(OLD), __float_as_int(SRC), CTRL, RM, BM, BC))
// whole-wave shift right by 1 (wf_sr1); lane 0 receives OLD
#define WSHIFT1(OLD, SRC) DPPF(OLD, SRC, 0x138, 0xF, 0xF, false)

__device__ __forceinline__ float readlaneF(float v, int l) {
    return __int_as_float(__builtin_amdgcn_readlane(__float_as_int(v), l));
}

// One 256-thread block (4 waves) per (qi,kj) pair. Wave w owns columns
// [256w, 256w+256); lane L owns j = 256w + 4L + e, e in [0,4).
// Anti-diagonal DP: D[i,j] = |x[i]-y[j]| + min3(up, left, diag).
// Within a wave, left/diag cross lanes via wf_sr1 DPP; across waves via the
// LDS boundary array bnd[w][row+BOFF] (wave w's col-255local values), with a
// 9-chunk skew so producers stay ahead. x streams through lanes in a 4-reg
// register circular buffer (one DPP shift per step, lane-0 inject from
// v_readlane of a per-chunk vector) -> no LDS reads in the inner steps.
__global__ __launch_bounds__(256) void dtw4_kernel(const float* __restrict__ q,
                                                   const float* __restrict__ kk,
                                                   float* __restrict__ dists) {
    __shared__ float xl[1280];
    __shared__ float bnd[3][BSTRIDE];
    const int tid = threadIdx.x;
    const int lane = tid & 63;
    const int wv = tid >> 6;
    const int pair = blockIdx.x;          // 0..63
    const float* __restrict__ x = q + (pair >> 3) * SEGLEN;
    const float* __restrict__ y = kk + (pair & 7) * SEGLEN;

    for (int t = tid; t < 1280; t += 256) xl[t] = (t < SEGLEN) ? x[t] : PADV;
    for (int t = tid; t < 3 * BSTRIDE; t += 256) (&bnd[0][0])[t] = BIGV;

    float yv[4];
    {
        const float4 y4 = *(const float4*)(y + wv * 256 + lane * 4);
        yv[0] = y4.x; yv[1] = y4.y; yv[2] = y4.z; yv[3] = y4.w;
    }

    float A[4], B[4], xs[4];
#pragma unroll
    for (int e = 0; e < 4; ++e) { A[e] = BIGV; B[e] = BIGV; xs[e] = PADV; }

    __syncthreads();

// One diagonal step. P1 = prev diagonal (d-1), P2 = prev2 (d-2) and output.
// Descending e so P2[e-1] (diag neighbor) is read before being overwritten.
#define STEP(s, P1, P2)  {                                                    \
    const float xinj = readlaneF(xv, (s));                                    \
    xs[(s) & 3] = WSHIFT1(xinj, xs[(s) & 3]);                                 \
    const float linj = (wv == 0) ? BIGV : readlaneF(bvv, (s) + 1);            \
    const float p1m = WSHIFT1(linj, P1[3]);                                   \
    const float p2m = WSHIFT1(dinj, P2[3]);                                   \
    _Pragma("unroll")                                                         \
    for (int e = 3; e >= 0; --e) {                                            \
        const float up = P1[e];                                               \
        const float lf = (e == 0) ? p1m : P1[e - 1];                          \
        const float dg = (e == 0) ? p2m : P2[e - 1];                          \
        P2[e] = fabsf(xs[((s) - e) & 3] - yv[e]) + fminf(fminf(up, lf), dg);  \
    }                                                                         \
    bb[(s)] = P2[3];                                                          \
    dinj = linj;                                                              \
}
#define STEP2(s) STEP(s, A, B) STEP((s) + 1, B, A)

    for (int k = 0; k < NSUP; ++k) {
        const int t = k - LAG * wv;
        if (t >= 0 && t < NCH) {
            // per-chunk vectors: x inject stream + previous strip's boundary
            const float xv = xl[CH * t + (lane & 31)];
            float bvv = 0.f;
            if (wv > 0) bvv = bnd[wv - 1][CH * t + lane + (BOFF - 1)];
            float bb[CH];
            // diag inject for s=0 (row CH*t-1); chained to linj afterwards
            float dinj = (wv == 0) ? ((t == 0) ? 0.f : BIGV)
                                   : readlaneF(bvv, 0);

            STEP2(0)  STEP2(2)  STEP2(4)  STEP2(6)
            STEP2(8)  STEP2(10) STEP2(12) STEP2(14)
            STEP2(16) STEP2(18) STEP2(20) STEP2(22)
            STEP2(24) STEP2(26) STEP2(28) STEP2(30)

            if (wv < 3) {
                if (lane == 63) {
                    // col-255local value of diag dl=CH*t+s is row CH*t+s-255
                    // -> index CH*t+s-255+BOFF = CH*t+s+1
#pragma unroll
                    for (int s = 0; s < CH; ++s) bnd[wv][CH * t + s + 1] = bb[s];
                }
            } else if (t == NCH - 1 && lane == 63) {
                // global cell (1023,1023): wave 3, local diag 1278 -> s=30
                dists[pair] = bb[30];
            }
        }
        __syncthreads();
    }
#undef STEP
#undef STEP2
}

// out[i*1024+p] = sum_j softmax_j(0.5*dists[i,:])[j] * values[j*1024+p]
__global__ __launch_bounds__(256) void softmax_out_kernel(const float* __restrict__ v,
                                                          const float* __restrict__ dists,
                                                          float* __restrict__ out) {
    const int o = blockIdx.x * blockDim.x + threadIdx.x;
    if (o >= NSEG * SEGLEN) return;
    const int i = o >> 10;
    const int p = o & 1023;

    float l[NSEG];
    float mx = -FLT_MAX;
#pragma unroll
    for (int j = 0; j < NSEG; ++j) {
        l[j] = 0.5f * dists[i * NSEG + j];
        mx = fmaxf(mx, l[j]);
    }
    float s = 0.f;
#pragma unroll
    for (int j = 0; j < NSEG; ++j) {
        l[j] = expf(l[j] - mx);
        s += l[j];
    }
    const float inv = 1.f / s;
    float acc = 0.f;
#pragma unroll
    for (int j = 0; j < NSEG; ++j) acc += (l[j] * inv) * v[j * SEGLEN + p];
    out[o] = acc;
}

extern "C" void kernel_launch(void* const* d_in, const int* in_sizes, int n_in,
                              void* d_out, int out_size, void* d_ws, size_t ws_size,
                              hipStream_t stream) {
    const float* q = (const float*)d_in[0];   // queries [1,32,8,32] f32
    const float* k = (const float*)d_in[1];   // keys
    const float* v = (const float*)d_in[2];   // values
    float* out = (float*)d_out;               // [8192] f32
    float* dists = (float*)d_ws;              // 64 floats scratch

    dtw4_kernel<<<dim3(NSEG * NSEG), dim3(256), 0, stream>>>(q, k, dists);
    softmax_out_kernel<<<dim3((NSEG * SEGLEN + 255) / 256), dim3(256), 0, stream>>>(v, dists, out);
}

// Round 6
// 92.531 us; speedup vs baseline: 7.6395x; 1.4278x over previous
//
#include <hip/hip_runtime.h>
#include <float.h>

#define NSEG 8
#define SEGLEN 1024   // B*Ls*H*D = 1*4*8*32
#define BIGV 1e30f    // "infinity" for invalid DP cells
#define PADV 1e18f    // x-pad sentinel (huge cost, no overflow)

#define CH 64         // diagonals per chunk (one flag handshake per chunk)
#define NCH 20        // chunks per wave: local diags 0..1279
#define BSTRIDE 1536  // boundary rows -256..1279 -> index row+256 in [0,1536)

#define DPPF(OLD, SRC, CTRL, RM, BM, BC)                                      \
    __int_as_float(__builtin_amdgcn_update_dpp(                               \
        __float_as_int(OLD), __float_as_int(SRC), CTRL, RM, BM, BC))
// whole-wave shift right by 1 (wf_sr1); lane 0 receives OLD
#define WSHIFT1(OLD, SRC) DPPF(OLD, SRC, 0x138, 0xF, 0xF, false)

__device__ __forceinline__ float readlaneF(float v, int l) {
    return __int_as_float(__builtin_amdgcn_readlane(__float_as_int(v), l));
}

// One 256-thread block (4 waves) per (qi,kj) pair. Wave w owns columns
// [256w, 256w+256); lane L owns j = 256w + 4L + e, e in [0,4).
// D[i,j] = |x[i]-y[j]| + min3(up, left, diag), computed along anti-diagonals.
// Cross-wave boundary values flow through bnd[w+1][row+256] in LDS; sync is a
// per-wave monotonic chunk counter (release store / acquire spin) -- no
// __syncthreads in the main loop, so the 4-wave pipeline free-runs.
// R5 bug: the spin target t+5 exceeds the producer's max published value
// (NCH=20) for t>=16 -> deadlock. Boundary data past the producer's last
// chunk is pad-row data that keeps its BIGV initialization, so the correct
// wait target is min(t+5, NCH).
__global__ __launch_bounds__(256) void dtw4_kernel(const float* __restrict__ q,
                                                   const float* __restrict__ kk,
                                                   float* __restrict__ dists) {
    __shared__ float xl[1280];
    __shared__ float bnd[5][BSTRIDE];  // bnd[0] = all-BIGV region for wave 0
    __shared__ float dump[128];        // write sink for lanes != 63
    __shared__ int flagsA[5];          // [0]=sentinel; [w+1]=chunks done by wave w
    const int tid = threadIdx.x;
    const int lane = tid & 63;
    const int wv = tid >> 6;
    const int pair = blockIdx.x;       // 0..63
    const float* __restrict__ x = q + (pair >> 3) * SEGLEN;
    const float* __restrict__ y = kk + (pair & 7) * SEGLEN;

    for (int t = tid; t < 1280; t += 256) xl[t] = (t < SEGLEN) ? x[t] : PADV;
    for (int t = tid; t < 5 * BSTRIDE; t += 256) (&bnd[0][0])[t] = BIGV;
    if (tid < 5) flagsA[tid] = (tid == 0) ? 0x7FFFFFFF : 0;

    float yv[4];
    {
        const float4 y4 = *(const float4*)(y + wv * 256 + lane * 4);
        yv[0] = y4.x; yv[1] = y4.y; yv[2] = y4.z; yv[3] = y4.w;
    }

    float A[4], B[4], xs[4];
#pragma unroll
    for (int e = 0; e < 4; ++e) { A[e] = BIGV; B[e] = BIGV; xs[e] = PADV; }

    __syncthreads();   // the only block-wide barrier

    const float* __restrict__ br = &bnd[wv][0];       // left neighbor's boundary

// One diagonal step (s compile-time). P1 = diag d-1, P2 = diag d-2 & output.
// Descending e so P2[e-1] (diag neighbor) is read before being overwritten.
#define STEP(s, P1, P2)  {                                                    \
    const float xinj = readlaneF(xv, (s));                                    \
    xs[(s) & 3] = WSHIFT1(xinj, xs[(s) & 3]);                                 \
    const float linj = ((s) == CH - 1) ? bvx : readlaneF(bvv, (s) + 1);       \
    const float p1m = WSHIFT1(linj, P1[3]);                                   \
    const float p2m = WSHIFT1(dinj, P2[3]);                                   \
    _Pragma("unroll")                                                         \
    for (int e = 3; e >= 0; --e) {                                            \
        const float up = P1[e];                                               \
        const float lf = (e == 0) ? p1m : P1[e - 1];                          \
        const float dg = (e == 0) ? p2m : P2[e - 1];                          \
        P2[e] = fabsf(xs[((s) - e) & 3] - yv[e]) + fminf(fminf(up, lf), dg);  \
    }                                                                         \
    va[(s)] = P2[3];                                                          \
    dinj = linj;                                                              \
}
#define STEP2(s) STEP(s, A, B) STEP((s) + 1, B, A)

#pragma unroll 1
    for (int t = 0; t < NCH; ++t) {
        // wait until left neighbor covers boundary rows up to 64t+63
        // (chunk t+4 done), capped at its total chunk count NCH: indices past
        // its last write are pad rows holding their BIGV initialization.
        const int need = (t + 5 < NCH) ? (t + 5) : NCH;
        while (__hip_atomic_load(&flagsA[wv], __ATOMIC_ACQUIRE,
                                 __HIP_MEMORY_SCOPE_WORKGROUP) < need)
            __builtin_amdgcn_s_sleep(2);

        const float xv = xl[CH * t + lane];                 // x inject stream
        const float bvv = br[CH * t + 255 + lane];          // rows 64t-1..64t+62
        const float bvx = br[CH * t + 319];                 // row 64t+63 (uniform)
        float dinj = readlaneF(bvv, 0);                     // row 64t-1 diag seed
        if (wv + t == 0) dinj = 0.f;                        // virtual D[-1,-1]=0
        // boundary write target: lane 63 -> bnd[wv+1][64t+1+s]; others -> dump
        float* va = (lane == 63) ? &bnd[wv + 1][CH * t + 1] : &dump[lane];

        STEP2(0)  STEP2(2)  STEP2(4)  STEP2(6)  STEP2(8)  STEP2(10)
        STEP2(12) STEP2(14) STEP2(16) STEP2(18) STEP2(20) STEP2(22)
        STEP2(24) STEP2(26) STEP2(28) STEP2(30) STEP2(32) STEP2(34)
        STEP2(36) STEP2(38) STEP2(40) STEP2(42) STEP2(44) STEP2(46)
        STEP2(48) STEP2(50) STEP2(52) STEP2(54) STEP2(56) STEP2(58)
        STEP2(60) STEP2(62)

        // publish chunk t (release orders the ds_writes above before the flag)
        __hip_atomic_store(&flagsA[wv + 1], t + 1, __ATOMIC_RELEASE,
                           __HIP_MEMORY_SCOPE_WORKGROUP);
    }
#undef STEP
#undef STEP2

    // global cell (1023,1023): wave 3, local diag 1278 (chunk 19, s=62 -> B)
    if (wv == 3 && lane == 63) dists[pair] = B[3];
}

// out[i*1024+p] = sum_j softmax_j(0.5*dists[i,:])[j] * values[j*1024+p]
__global__ __launch_bounds__(256) void softmax_out_kernel(const float* __restrict__ v,
                                                          const float* __restrict__ dists,
                                                          float* __restrict__ out) {
    const int o = blockIdx.x * blockDim.x + threadIdx.x;
    if (o >= NSEG * SEGLEN) return;
    const int i = o >> 10;
    const int p = o & 1023;

    float l[NSEG];
    float mx = -FLT_MAX;
#pragma unroll
    for (int j = 0; j < NSEG; ++j) {
        l[j] = 0.5f * dists[i * NSEG + j];
        mx = fmaxf(mx, l[j]);
    }
    float s = 0.f;
#pragma unroll
    for (int j = 0; j < NSEG; ++j) {
        l[j] = expf(l[j] - mx);
        s += l[j];
    }
    const float inv = 1.f / s;
    float acc = 0.f;
#pragma unroll
    for (int j = 0; j < NSEG; ++j) acc += (l[j] * inv) * v[j * SEGLEN + p];
    out[o] = acc;
}

extern "C" void kernel_launch(void* const* d_in, const int* in_sizes, int n_in,
                              void* d_out, int out_size, void* d_ws, size_t ws_size,
                              hipStream_t stream) {
    const float* q = (const float*)d_in[0];   // queries [1,32,8,32] f32
    const float* k = (const float*)d_in[1];   // keys
    const float* v = (const float*)d_in[2];   // values
    float* out = (float*)d_out;               // [8192] f32
    float* dists = (float*)d_ws;              // 64 floats scratch

    dtw4_kernel<<<dim3(NSEG * NSEG), dim3(256), 0, stream>>>(q, k, dists);
    softmax_out_kernel<<<dim3((NSEG * SEGLEN + 255) / 256), dim3(256), 0, stream>>>(v, dists, out);
}